// Round 1
// baseline (217.994 us; speedup 1.0000x reference)
//
#include <hip/hip_runtime.h>
#include <hip/hip_bf16.h>

typedef __attribute__((ext_vector_type(4))) short bfx4;
typedef __attribute__((ext_vector_type(8))) short short8;
typedef __attribute__((ext_vector_type(4))) float floatx4;
typedef __attribute__((ext_vector_type(4))) unsigned int uintx4;

constexpr int Sdim = 2048;
constexpr int Hdim = 1024;
constexpr int NH   = 16;
constexpr int HD   = 64;

// fp32 -> bf16 round-half-up (1 add + shift)
__device__ __forceinline__ unsigned short f2bf(float f) {
    return (unsigned short)((__builtin_bit_cast(unsigned int, f) + 0x8000u) >> 16);
}

// 8 fp32 -> 8 bf16, round-half-up, packed with v_perm_b32
__device__ __forceinline__ short8 cvt8(const float* __restrict__ p) {
    uintx4 a = *(const uintx4*)p;
    uintx4 b = *(const uintx4*)(p + 4);
#pragma unroll
    for (int i = 0; i < 4; ++i) { a[i] += 0x8000u; b[i] += 0x8000u; }
    union { unsigned int u[4]; short8 s; } r;
    r.u[0] = __builtin_amdgcn_perm(a[1], a[0], 0x07060302u);
    r.u[1] = __builtin_amdgcn_perm(a[3], a[2], 0x07060302u);
    r.u[2] = __builtin_amdgcn_perm(b[1], b[0], 0x07060302u);
    r.u[3] = __builtin_amdgcn_perm(b[3], b[2], 0x07060302u);
    return r.s;
}

// async global->LDS, 16 B per lane; LDS dest = uniform base + lane*16
__device__ __forceinline__ void async16(const unsigned short* g, unsigned short* l) {
    __builtin_amdgcn_global_load_lds(
        (const __attribute__((address_space(1))) unsigned int*)g,
        (__attribute__((address_space(3))) unsigned int*)l,
        16, 0, 0);
}

// ---------------------------------------------------------------------------
// Kernel 1: merged Q/K/V projection, DOUBLE-BUFFERED (one barrier per step).
// X staged once per step, shared by 3 GEMMs (12 MFMA/step/wave).  BK=32.
// N-SPLIT wave ownership: each wave owns 16 output cols (one nt) of all 3
// matrices -> A-frags shared (4 reads), B-frags private (3 reads):
//   7 ds_read_b128 / wave / step (was 13; 28/block vs 52 -> -46% LDS reads).
// LDS 2 x 20480 B = 40960 B -> exactly 4 blocks/CU.
//   q -> d_out as BF16 packed into the block's own output region (race-free)
//   k -> ws [b,h,s,d] bf16;  v -> ws TRANSPOSED [b,h,d,s] bf16
// grid = (16 heads, 64 m-tiles); block = 256.
// ---------------------------------------------------------------------------
__global__ __launch_bounds__(256, 4) void qkv_proj_kernel(
    const float* __restrict__ Wq,
    const float* __restrict__ Wk,
    const float* __restrict__ Wv,
    const float* __restrict__ bq,
    const float* __restrict__ bv,
    const float* __restrict__ X,
    unsigned short* __restrict__ qo,     // = d_out viewed as ushort
    unsigned short* __restrict__ ko,
    unsigned short* __restrict__ vo)
{
    __shared__ __align__(16) unsigned short smem[2 * 10240];  // 40960 B
    // buffer p: +p*10240; inside: Xs +0, Ws0 +2560, Ws1 +5120, Ws2 +7680

    const int tid  = threadIdx.x;
    const int wave = tid >> 6;
    const int lane = tid & 63;
    const int quad = lane >> 4;
    const int l16  = lane & 15;

    const int h  = blockIdx.x;
    const int n0 = h * 64;
    const int m0 = blockIdx.y * 64;

    floatx4 acc[3][4];                   // [matrix][m-tile]
#pragma unroll
    for (int g = 0; g < 3; ++g)
#pragma unroll
        for (int mt = 0; mt < 4; ++mt) acc[g][mt] = (floatx4){0.f, 0.f, 0.f, 0.f};

    const int srow = tid >> 2;        // 0..63
    const int scol = (tid & 3) * 8;   // 0..24

    const float* Xr  = X  + (size_t)(m0 + srow) * Hdim + scol;
    const float* Wr0 = Wq + (size_t)(n0 + srow) * Hdim + scol;
    const float* Wr1 = Wk + (size_t)(n0 + srow) * Hdim + scol;
    const float* Wr2 = Wv + (size_t)(n0 + srow) * Hdim + scol;

    // stage step 0 -> buffer 0
    {
        unsigned short* B0 = smem;
        *(short8*)(B0 +        srow * 40 + scol) = cvt8(Xr);
        *(short8*)(B0 + 2560 + srow * 40 + scol) = cvt8(Wr0);
        *(short8*)(B0 + 5120 + srow * 40 + scol) = cvt8(Wr1);
        *(short8*)(B0 + 7680 + srow * 40 + scol) = cvt8(Wr2);
    }

    for (int s = 0; s < 32; ++s) {
        __syncthreads();                              // step-s staging visible
        const unsigned short* buf = smem + (s & 1) * 10240;

        short8 px, p0, p1, p2;
        if (s < 31) {
            const int kn = (s + 1) * 32;
            px = cvt8(Xr  + kn);
            p0 = cvt8(Wr0 + kn);
            p1 = cvt8(Wr1 + kn);
            p2 = cvt8(Wr2 + kn);
        }

        // B-fragments: this wave's private 16-col slice of each W
        const int boff = (wave * 16 + l16) * 40 + quad * 8;
        const short8 b0 = *(const short8*)(buf + 2560 + boff);
        const short8 b1 = *(const short8*)(buf + 5120 + boff);
        const short8 b2 = *(const short8*)(buf + 7680 + boff);
#pragma unroll
        for (int mt = 0; mt < 4; ++mt) {
            const short8 af = *(const short8*)(buf + (mt * 16 + l16) * 40 + quad * 8);
            acc[0][mt] = __builtin_amdgcn_mfma_f32_16x16x32_bf16(af, b0, acc[0][mt], 0, 0, 0);
            acc[1][mt] = __builtin_amdgcn_mfma_f32_16x16x32_bf16(af, b1, acc[1][mt], 0, 0, 0);
            acc[2][mt] = __builtin_amdgcn_mfma_f32_16x16x32_bf16(af, b2, acc[2][mt], 0, 0, 0);
        }

        if (s < 31) {                                  // store into other buffer
            unsigned short* nb = smem + ((s & 1) ^ 1) * 10240;
            *(short8*)(nb +        srow * 40 + scol) = px;
            *(short8*)(nb + 2560 + srow * 40 + scol) = p0;
            *(short8*)(nb + 5120 + srow * 40 + scol) = p1;
            *(short8*)(nb + 7680 + srow * 40 + scol) = p2;
        }
    }

    const int b  = m0 >> 11;
    const int s0 = m0 & 2047;
    const int dd = wave * 16 + l16;      // col within the head (0..63)

    // ---- Q epilogue: bf16 packed into the block's own d_out region ----
    // ushort index = ((b*S+s)*H + h*64)*2 + dd,  dd in [0,64)
    {
        const float bqv = bq[n0 + dd];
#pragma unroll
        for (int mt = 0; mt < 4; ++mt)
#pragma unroll
            for (int reg = 0; reg < 4; ++reg) {
                const int srw = s0 + mt * 16 + quad * 4 + reg;
                qo[((size_t)(b * Sdim + srw) * Hdim + n0) * 2 + dd] =
                    f2bf((acc[0][mt][reg] + bqv) * 0.125f);
            }
    }
    // ---- K epilogue: bf16 [b,h,s,d] ----
#pragma unroll
    for (int mt = 0; mt < 4; ++mt)
#pragma unroll
        for (int reg = 0; reg < 4; ++reg) {
            const int srw = s0 + mt * 16 + quad * 4 + reg;
            ko[((size_t)(b * NH + h) * Sdim + srw) * HD + dd] = f2bf(acc[1][mt][reg]);
        }
    // ---- V epilogue: transpose via LDS buf0 (disjoint from last-step buf1) ----
    unsigned short* Vl = smem;   // 64*74 = 4736 shorts
    {
        const float bvv = bv[n0 + dd];
#pragma unroll
        for (int mt = 0; mt < 4; ++mt) {
            bfx4 p;
#pragma unroll
            for (int reg = 0; reg < 4; ++reg) p[reg] = (short)f2bf(acc[2][mt][reg] + bvv);
            *(bfx4*)(Vl + dd * 74 + mt * 16 + quad * 4) = p;
        }
    }
    __syncthreads();
#pragma unroll
    for (int i = 0; i < 2; ++i) {
        const int t   = tid + 256 * i;
        const int d2  = t >> 3;
        const int off = (t & 7) * 8;
        *(short8*)(vo + ((size_t)(b * NH + h) * HD + d2) * Sdim + s0 + off) =
            *(const short8*)(Vl + d2 * 74 + off);
    }
}

// ---------------------------------------------------------------------------
// Kernel 2: flash attention, 2q x 2k wave split, fixed-shift softmax.
// K/V staged via global_load_lds DMA (swizzle realized by permuting the
// per-lane GLOBAL addresses), double-buffered, ONE barrier per tile.
// Q read as bf16 from d_out (written there by proj, race-free self-region).
// LDS = 2*8K (K) + 2*8K (V) + 8K (Pt) = 40960 B -> 4 blocks/CU exactly.
// grid = 1024 (flat%32 = bh -> XCD-local K/V reuse).
// ---------------------------------------------------------------------------
__global__ __launch_bounds__(256) void attn_kernel(
    const unsigned short* __restrict__ kw,
    const unsigned short* __restrict__ vw,
    const float* __restrict__ mask,
    float* __restrict__ out)
{
    __shared__ __align__(16) unsigned short smem[20480];   // 40960 B
    unsigned short* KtA = smem;            // 2 x 4096 (64 keys x 64 d, swizzled)
    unsigned short* VtA = smem + 8192;     // 2 x 4096 (64 d x 64 keys, swizzled)
    unsigned short* Pt  = smem + 16384;    // 4 waves x 2 g x 16 q x 32

    const int tid  = threadIdx.x;
    const int wave = tid >> 6;
    const int wq   = wave >> 1;            // q-half 0/1
    const int wk   = wave & 1;             // key-half 0/1
    const int lane = tid & 63;
    const int quad = lane >> 4;
    const int l16  = lane & 15;
    const int m7   = l16 & 7;

    const int flat = blockIdx.x;
    const int bh   = flat & 31;
    const int b    = bh >> 4;
    const int h    = bh & 15;
    const int q0   = (flat >> 5) * 64;

    const unsigned short* K  = kw + (size_t)bh * Sdim * HD;   // [key][d]
    const unsigned short* Vg = vw + (size_t)bh * HD * Sdim;   // [d][key]
    const float* mg = mask + (size_t)b * Sdim;

    constexpr float SHIFT = 12.0f;

    // ---- Q fragments (B-operand) directly as bf16 from d_out ----
    short8 qf[2][2];
    {
        const unsigned short* qsrc = (const unsigned short*)out;
#pragma unroll
        for (int g = 0; g < 2; ++g)
#pragma unroll
            for (int c = 0; c < 2; ++c)
                qf[g][c] = *(const short8*)(qsrc
                    + ((size_t)(b * Sdim + q0 + wq * 32 + g * 16 + l16) * Hdim + h * HD) * 2
                    + c * 32 + quad * 8);
    }

    // ---- DMA lane mapping: lane i covers row rk = wave*16 + i/8 (j=0), +8 (j=1);
    //      global chunk = (i&7) ^ (rk&7)  -> realizes the XOR-swizzled LDS image
    const int rk = wave * 16 + (lane >> 3);
    const int sw = ((lane & 7) ^ (rk & 7)) * 8;
    const unsigned short* kgp = K  + (size_t)rk * HD   + sw;
    const unsigned short* vgp = Vg + (size_t)rk * Sdim + sw;

    // stage tile 0 -> buffer 0
    {
        unsigned short* Kb = KtA + wave * 1024;
        unsigned short* Vb = VtA + wave * 1024;
        async16(kgp,            Kb);
        async16(kgp + 8 * HD,   Kb + 512);
        async16(vgp,            Vb);
        async16(vgp + 8 * Sdim, Vb + 512);
        kgp += (size_t)64 * HD;
        vgp += 64;
    }

    unsigned short* Pw = Pt + wave * 1024;   // 2 g x 16 q x 32

    float lsum[2] = {0.f, 0.f};
    floatx4 oT[4][2];                        // [d-group][q-group]
#pragma unroll
    for (int mgi = 0; mgi < 4; ++mgi)
#pragma unroll
        for (int g = 0; g < 2; ++g) oT[mgi][g] = (floatx4){0.f, 0.f, 0.f, 0.f};

    for (int it = 0; it < 32; ++it) {
        __syncthreads();                     // vmcnt drain + barrier: tile ready
        const int kt = it * 64;
        const unsigned short* Kb = KtA + (it & 1) * 4096;
        const unsigned short* Vb = VtA + (it & 1) * 4096;

        if (it < 31) {                       // DMA next tile into other buffer
            unsigned short* Kn = KtA + ((it & 1) ^ 1) * 4096 + wave * 1024;
            unsigned short* Vn = VtA + ((it & 1) ^ 1) * 4096 + wave * 1024;
            async16(kgp,            Kn);
            async16(kgp + 8 * HD,   Kn + 512);
            async16(vgp,            Vn);
            async16(vgp + 8 * Sdim, Vn + 512);
            kgp += (size_t)64 * HD;
            vgp += 64;
        }

        // ---- S^T = K·Q^T for this wave's 32-key slice ----
        floatx4 st[2][2];
#pragma unroll
        for (int kg = 0; kg < 2; ++kg) {
            const unsigned short* kr = Kb + (wk * 32 + kg * 16 + l16) * 64;
            short8 ka0 = *(const short8*)(kr + (quad ^ m7) * 8);
            short8 ka1 = *(const short8*)(kr + ((4 + quad) ^ m7) * 8);
#pragma unroll
            for (int g = 0; g < 2; ++g) {
                floatx4 s = (floatx4){0.f, 0.f, 0.f, 0.f};
                s = __builtin_amdgcn_mfma_f32_16x16x32_bf16(ka0, qf[g][0], s, 0, 0, 0);
                s = __builtin_amdgcn_mfma_f32_16x16x32_bf16(ka1, qf[g][1], s, 0, 0, 0);
                st[kg][g] = s;
            }
        }

        // ---- exp + vectorized P^T store + per-lane l partials ----
        floatx4 mk[2];
#pragma unroll
        for (int kg = 0; kg < 2; ++kg) {
            mk[kg] = *(const floatx4*)(mg + kt + wk * 32 + kg * 16 + quad * 4);
#pragma unroll
            for (int reg = 0; reg < 4; ++reg) mk[kg][reg] -= SHIFT;
        }
#pragma unroll
        for (int kg = 0; kg < 2; ++kg)
#pragma unroll
            for (int g = 0; g < 2; ++g) {
                bfx4 pk;
#pragma unroll
                for (int reg = 0; reg < 4; ++reg) {
                    const float p = __expf(st[kg][g][reg] + mk[kg][reg]);
                    lsum[g] += p;
                    pk[reg] = (short)f2bf(p);
                }
                *(bfx4*)(Pw + g * 512 + l16 * 32 + kg * 16 + quad * 4) = pk;
            }

        // ---- O^T += V^T·P^T (Pt per-wave: no barrier) ----
        short8 pb[2];
#pragma unroll
        for (int g = 0; g < 2; ++g)
            pb[g] = *(const short8*)(Pw + g * 512 + l16 * 32 + quad * 8);
#pragma unroll
        for (int mgi = 0; mgi < 4; ++mgi) {
            short8 va = *(const short8*)(Vb + (mgi * 16 + l16) * 64 + ((wk * 4 + quad) ^ m7) * 8);
#pragma unroll
            for (int g = 0; g < 2; ++g)
                oT[mgi][g] = __builtin_amdgcn_mfma_f32_16x16x32_bf16(va, pb[g], oT[mgi][g], 0, 0, 0);
        }
    }

    // ---- reduce l across quads (q-row = g*16+l16 is quad-invariant) ----
#pragma unroll
    for (int g = 0; g < 2; ++g) {
        lsum[g] += __shfl_xor(lsum[g], 16);
        lsum[g] += __shfl_xor(lsum[g], 32);
    }

    __syncthreads();                         // all waves done with K/V buffers

    // ---- cross-wave (key-half) reduction via LDS, then write out ----
    float* Ored = (float*)smem;              // [2 wq][32 q][68] fp32
    float* Lred = Ored + 2 * 32 * 68;        // [64]
    if (wk == 0) {
#pragma unroll
        for (int mgi = 0; mgi < 4; ++mgi)
#pragma unroll
            for (int g = 0; g < 2; ++g)
                *(floatx4*)(Ored + (size_t)(wq * 32 + g * 16 + l16) * 68 + mgi * 16 + quad * 4) = oT[mgi][g];
        if (quad == 0) {
#pragma unroll
            for (int g = 0; g < 2; ++g) Lred[wq * 32 + g * 16 + l16] = lsum[g];
        }
    }
    __syncthreads();
    if (wk == 1) {
        float linv[2];
#pragma unroll
        for (int g = 0; g < 2; ++g)
            linv[g] = 1.0f / (lsum[g] + Lred[wq * 32 + g * 16 + l16]);
#pragma unroll
        for (int mgi = 0; mgi < 4; ++mgi)
#pragma unroll
            for (int g = 0; g < 2; ++g) {
                floatx4 o = *(const floatx4*)(Ored + (size_t)(wq * 32 + g * 16 + l16) * 68 + mgi * 16 + quad * 4);
                floatx4 r;
#pragma unroll
                for (int reg = 0; reg < 4; ++reg)
                    r[reg] = (o[reg] + oT[mgi][g][reg]) * linv[g];
                *(floatx4*)(out + (size_t)(b * Sdim + q0 + wq * 32 + g * 16 + l16) * Hdim
                            + h * HD + mgi * 16 + quad * 4) = r;
            }
    }
}

extern "C" void kernel_launch(void* const* d_in, const int* in_sizes, int n_in,
                              void* d_out, int out_size, void* d_ws, size_t ws_size,
                              hipStream_t stream) {
    const float* X    = (const float*)d_in[0];
    const float* mask = (const float*)d_in[1];
    const float* Wq   = (const float*)d_in[2];
    const float* bq   = (const float*)d_in[3];
    const float* Wk   = (const float*)d_in[4];
    const float* Wv   = (const float*)d_in[5];
    const float* bv   = (const float*)d_in[6];
    float* out = (float*)d_out;

    // workspace: k [b,h,s,d] + v^T [b,h,d,s] bf16 -> 16 MiB total
    unsigned short* kws = (unsigned short*)d_ws;
    unsigned short* vws = kws + (size_t)4096 * 1024;

    qkv_proj_kernel<<<dim3(16, 64), 256, 0, stream>>>(
        Wq, Wk, Wv, bq, bv, X, (unsigned short*)d_out, kws, vws);
    attn_kernel<<<dim3(1024), 256, 0, stream>>>(
        kws, vws, mask, out);
}

// Round 6
// 205.081 us; speedup vs baseline: 1.0630x; 1.0630x over previous
//
#include <hip/hip_runtime.h>
#include <hip/hip_bf16.h>

typedef __attribute__((ext_vector_type(4))) short bfx4;
typedef __attribute__((ext_vector_type(8))) short short8;
typedef __attribute__((ext_vector_type(4))) float floatx4;
typedef __attribute__((ext_vector_type(16))) float f32x16;
typedef __attribute__((ext_vector_type(4))) unsigned int uintx4;

constexpr int Sdim = 2048;
constexpr int Hdim = 1024;
constexpr int NH   = 16;
constexpr int HD   = 64;

// fp32 -> bf16 round-half-up (1 add + shift)
__device__ __forceinline__ unsigned short f2bf(float f) {
    return (unsigned short)((__builtin_bit_cast(unsigned int, f) + 0x8000u) >> 16);
}

// 8 fp32 -> 8 bf16, round-half-up, packed with v_perm_b32
__device__ __forceinline__ short8 cvt8(const float* __restrict__ p) {
    uintx4 a = *(const uintx4*)p;
    uintx4 b = *(const uintx4*)(p + 4);
#pragma unroll
    for (int i = 0; i < 4; ++i) { a[i] += 0x8000u; b[i] += 0x8000u; }
    union { unsigned int u[4]; short8 s; } r;
    r.u[0] = __builtin_amdgcn_perm(a[1], a[0], 0x07060302u);
    r.u[1] = __builtin_amdgcn_perm(a[3], a[2], 0x07060302u);
    r.u[2] = __builtin_amdgcn_perm(b[1], b[0], 0x07060302u);
    r.u[3] = __builtin_amdgcn_perm(b[3], b[2], 0x07060302u);
    return r.s;
}

// async global->LDS, 16 B per lane; LDS dest = uniform base + lane*16
__device__ __forceinline__ void async16(const unsigned short* g, unsigned short* l) {
    __builtin_amdgcn_global_load_lds(
        (const __attribute__((address_space(1))) unsigned int*)g,
        (__attribute__((address_space(3))) unsigned int*)l,
        16, 0, 0);
}

// pack 2 f32 -> 2 bf16 (RNE) in one instruction
__device__ __forceinline__ unsigned int cvtpk(float lo, float hi) {
    unsigned int r;
    asm("v_cvt_pk_bf16_f32 %0, %1, %2" : "=v"(r) : "v"(lo), "v"(hi));
    return r;
}

// ---------------------------------------------------------------------------
// Kernel 1: merged Q/K/V projection (UNCHANGED — control).
// ---------------------------------------------------------------------------
__global__ __launch_bounds__(256, 4) void qkv_proj_kernel(
    const float* __restrict__ Wq,
    const float* __restrict__ Wk,
    const float* __restrict__ Wv,
    const float* __restrict__ bq,
    const float* __restrict__ bv,
    const float* __restrict__ X,
    unsigned short* __restrict__ qo,     // = d_out viewed as ushort
    unsigned short* __restrict__ ko,
    unsigned short* __restrict__ vo)
{
    __shared__ __align__(16) unsigned short smem[2 * 10240];  // 40960 B

    const int tid  = threadIdx.x;
    const int wave = tid >> 6;
    const int lane = tid & 63;
    const int quad = lane >> 4;
    const int l16  = lane & 15;

    const int h  = blockIdx.x;
    const int n0 = h * 64;
    const int m0 = blockIdx.y * 64;

    floatx4 acc[3][4];                   // [matrix][m-tile]
#pragma unroll
    for (int g = 0; g < 3; ++g)
#pragma unroll
        for (int mt = 0; mt < 4; ++mt) acc[g][mt] = (floatx4){0.f, 0.f, 0.f, 0.f};

    const int srow = tid >> 2;        // 0..63
    const int scol = (tid & 3) * 8;   // 0..24

    const float* Xr  = X  + (size_t)(m0 + srow) * Hdim + scol;
    const float* Wr0 = Wq + (size_t)(n0 + srow) * Hdim + scol;
    const float* Wr1 = Wk + (size_t)(n0 + srow) * Hdim + scol;
    const float* Wr2 = Wv + (size_t)(n0 + srow) * Hdim + scol;

    {
        unsigned short* B0 = smem;
        *(short8*)(B0 +        srow * 40 + scol) = cvt8(Xr);
        *(short8*)(B0 + 2560 + srow * 40 + scol) = cvt8(Wr0);
        *(short8*)(B0 + 5120 + srow * 40 + scol) = cvt8(Wr1);
        *(short8*)(B0 + 7680 + srow * 40 + scol) = cvt8(Wr2);
    }

    for (int s = 0; s < 32; ++s) {
        __syncthreads();
        const unsigned short* buf = smem + (s & 1) * 10240;

        short8 px, p0, p1, p2;
        if (s < 31) {
            const int kn = (s + 1) * 32;
            px = cvt8(Xr  + kn);
            p0 = cvt8(Wr0 + kn);
            p1 = cvt8(Wr1 + kn);
            p2 = cvt8(Wr2 + kn);
        }

        const int boff = (wave * 16 + l16) * 40 + quad * 8;
        const short8 b0 = *(const short8*)(buf + 2560 + boff);
        const short8 b1 = *(const short8*)(buf + 5120 + boff);
        const short8 b2 = *(const short8*)(buf + 7680 + boff);
#pragma unroll
        for (int mt = 0; mt < 4; ++mt) {
            const short8 af = *(const short8*)(buf + (mt * 16 + l16) * 40 + quad * 8);
            acc[0][mt] = __builtin_amdgcn_mfma_f32_16x16x32_bf16(af, b0, acc[0][mt], 0, 0, 0);
            acc[1][mt] = __builtin_amdgcn_mfma_f32_16x16x32_bf16(af, b1, acc[1][mt], 0, 0, 0);
            acc[2][mt] = __builtin_amdgcn_mfma_f32_16x16x32_bf16(af, b2, acc[2][mt], 0, 0, 0);
        }

        if (s < 31) {
            unsigned short* nb = smem + ((s & 1) ^ 1) * 10240;
            *(short8*)(nb +        srow * 40 + scol) = px;
            *(short8*)(nb + 2560 + srow * 40 + scol) = p0;
            *(short8*)(nb + 5120 + srow * 40 + scol) = p1;
            *(short8*)(nb + 7680 + srow * 40 + scol) = p2;
        }
    }

    const int b  = m0 >> 11;
    const int s0 = m0 & 2047;
    const int dd = wave * 16 + l16;

    {
        const float bqv = bq[n0 + dd];
#pragma unroll
        for (int mt = 0; mt < 4; ++mt)
#pragma unroll
            for (int reg = 0; reg < 4; ++reg) {
                const int srw = s0 + mt * 16 + quad * 4 + reg;
                qo[((size_t)(b * Sdim + srw) * Hdim + n0) * 2 + dd] =
                    f2bf((acc[0][mt][reg] + bqv) * 0.125f);
            }
    }
#pragma unroll
    for (int mt = 0; mt < 4; ++mt)
#pragma unroll
        for (int reg = 0; reg < 4; ++reg) {
            const int srw = s0 + mt * 16 + quad * 4 + reg;
            ko[((size_t)(b * NH + h) * Sdim + srw) * HD + dd] = f2bf(acc[1][mt][reg]);
        }
    unsigned short* Vl = smem;   // 64*74 shorts
    {
        const float bvv = bv[n0 + dd];
#pragma unroll
        for (int mt = 0; mt < 4; ++mt) {
            bfx4 p;
#pragma unroll
            for (int reg = 0; reg < 4; ++reg) p[reg] = (short)f2bf(acc[2][mt][reg] + bvv);
            *(bfx4*)(Vl + dd * 74 + mt * 16 + quad * 4) = p;
        }
    }
    __syncthreads();
#pragma unroll
    for (int i = 0; i < 2; ++i) {
        const int t   = tid + 256 * i;
        const int d2  = t >> 3;
        const int off = (t & 7) * 8;
        *(short8*)(vo + ((size_t)(b * NH + h) * HD + d2) * Sdim + s0 + off) =
            *(const short8*)(Vl + d2 * 74 + off);
    }
}

// ---------------------------------------------------------------------------
// Kernel 2: flash attention on 32x32x16 MFMA.
// S^T = K·Q^T per wave (32 keys x 32 q): C layout col=lane&31 (=q),
// row=(reg&3)+8*(reg>>2)+4*(lane>>5) (=key). P^T B-fragments for PV are
// assembled IN-REGISTER via __shfl_xor(32) + select.
// R4 BUGFIX: vOff now includes the wave's key-half offset (wk*4 in the
// chunk index -> keys wk*32 + kc*16 + l5*8 + 0..7). R3/R4 read keys 0..31
// for BOTH wave halves -> O(1) output error, invariant to the exchange
// implementation (explains identical absmax across R3/R4).
// NO P LDS round-trip. K/V staged via global_load_lds DMA (XOR-swizzled
// global addresses), double-buffered, one barrier per tile. LDS = 32 KiB.
// grid = 1024 (flat%32 = bh -> XCD-local K/V reuse).
// ---------------------------------------------------------------------------
__global__ __launch_bounds__(256) void attn_kernel(
    const unsigned short* __restrict__ kw,
    const unsigned short* __restrict__ vw,
    const float* __restrict__ mask,
    float* __restrict__ out)
{
    __shared__ __align__(16) unsigned short smem[16384];   // 32768 B
    unsigned short* KtA = smem;            // 2 x 4096 shorts (64 keys x 64 d, swizzled)
    unsigned short* VtA = smem + 8192;     // 2 x 4096 shorts (64 d x 64 keys, swizzled)

    const int tid  = threadIdx.x;
    const int wave = tid >> 6;
    const int wq   = wave >> 1;            // q-half 0/1
    const int wk   = wave & 1;             // key-half 0/1
    const int lane = tid & 63;
    const int l5   = lane >> 5;            // lane-half
    const int q31  = lane & 31;            // this lane's q column (C layout)
    const int m7l  = lane & 7;

    const int flat = blockIdx.x;
    const int bh   = flat & 31;
    const int b    = bh >> 4;
    const int h    = bh & 15;
    const int q0   = (flat >> 5) * 64;

    const unsigned short* K  = kw + (size_t)bh * Sdim * HD;   // [key][d]
    const unsigned short* Vg = vw + (size_t)bh * HD * Sdim;   // [d][key]
    const float* mg = mask + (size_t)b * Sdim;

    constexpr float SHIFT = 12.0f;

    // ---- Q fragments (B-operand, 32x32x16): lane holds col q31, k = i*16+l5*8 ----
    short8 qf[4];
    {
        const unsigned short* qsrc = (const unsigned short*)out;
        const size_t qbase =
            ((size_t)(b * Sdim + q0 + wq * 32 + q31) * Hdim + h * HD) * 2;
#pragma unroll
        for (int i = 0; i < 4; ++i)
            qf[i] = *(const short8*)(qsrc + qbase + i * 16 + l5 * 8);
    }

    // ---- DMA lane mapping: lane covers row rk, global chunk XOR-swizzled ----
    const int rk = wave * 16 + (lane >> 3);
    const int sw = ((lane & 7) ^ (rk & 7)) * 8;
    const unsigned short* kgp = K  + (size_t)rk * HD   + sw;
    const unsigned short* vgp = Vg + (size_t)rk * Sdim + sw;

    // stage tile 0 -> buffer 0
    {
        unsigned short* Kb = KtA + wave * 1024;
        unsigned short* Vb = VtA + wave * 1024;
        async16(kgp,            Kb);
        async16(kgp + 8 * HD,   Kb + 512);
        async16(vgp,            Vb);
        async16(vgp + 8 * Sdim, Vb + 512);
        kgp += (size_t)64 * HD;
        vgp += 64;
    }

    // tile-invariant LDS read offsets (shorts); row&7 == lane&7 for both
    int kOff[4], vOff[4];
#pragma unroll
    for (int i = 0; i < 4; ++i)
        kOff[i] = (wk * 32 + q31) * 64 + (((2 * i + l5) ^ m7l) * 8);
#pragma unroll
    for (int dblk = 0; dblk < 2; ++dblk)
#pragma unroll
        for (int kc = 0; kc < 2; ++kc)
            vOff[dblk * 2 + kc] =
                (dblk * 32 + q31) * 64 + (((wk * 4 + 2 * kc + l5) ^ m7l) * 8);

    const float* mgp = mg + wk * 32 + l5 * 4;

    float lsum = 0.f;
    f32x16 oT[2];                          // O^T per 32-d block; col=q31
#pragma unroll
    for (int dblk = 0; dblk < 2; ++dblk)
#pragma unroll
        for (int r = 0; r < 16; ++r) oT[dblk][r] = 0.f;

    for (int it = 0; it < 32; ++it) {
        __syncthreads();                   // vmcnt drain + barrier: tile ready
        const int kt = it * 64;
        const unsigned short* Kb = KtA + (it & 1) * 4096;
        const unsigned short* Vb = VtA + (it & 1) * 4096;

        if (it < 31) {                     // DMA next tile into other buffer
            unsigned short* Kn = KtA + ((it & 1) ^ 1) * 4096 + wave * 1024;
            unsigned short* Vn = VtA + ((it & 1) ^ 1) * 4096 + wave * 1024;
            async16(kgp,            Kn);
            async16(kgp + 8 * HD,   Kn + 512);
            async16(vgp,            Vn);
            async16(vgp + 8 * Sdim, Vn + 512);
            kgp += (size_t)64 * HD;
            vgp += 64;
        }

        // ---- S^T = K·Q^T: 4 chained 32x32x16 over d ----
        f32x16 st;
#pragma unroll
        for (int r = 0; r < 16; ++r) st[r] = 0.f;
#pragma unroll
        for (int i = 0; i < 4; ++i) {
            const short8 ka = *(const short8*)(Kb + kOff[i]);
            st = __builtin_amdgcn_mfma_f32_32x32x16_bf16(ka, qf[i], st, 0, 0, 0);
        }

        // ---- exp + in-register bf16 pack; st reg r -> key row (r&3)+8*(r>>2)+4*l5
        unsigned int w[8];
#pragma unroll
        for (int j = 0; j < 4; ++j) {
            const floatx4 mv = *(const floatx4*)(mgp + kt + j * 8);
            float e[4];
#pragma unroll
            for (int r = 0; r < 4; ++r) {
                e[r] = __expf(st[j * 4 + r] + (mv[r] - SHIFT));
                lsum += e[r];
            }
            w[2 * j]     = cvtpk(e[0], e[1]);
            w[2 * j + 1] = cvtpk(e[2], e[3]);
        }

        // ---- cross-half exchange: shfl_xor(32) + select ----
        // lane owns keys kc*16 + {4*l5+0..3, 8+4*l5+0..3}; B-frag needs l5*8+0..7
        union { unsigned int u[4]; short8 s; } pb0, pb1;
        {
            const unsigned int p0 = __shfl_xor(w[0], 32);
            const unsigned int p1 = __shfl_xor(w[1], 32);
            const unsigned int p2 = __shfl_xor(w[2], 32);
            const unsigned int p3 = __shfl_xor(w[3], 32);
            pb0.u[0] = l5 ? p2 : w[0];
            pb0.u[1] = l5 ? p3 : w[1];
            pb0.u[2] = l5 ? w[2] : p0;
            pb0.u[3] = l5 ? w[3] : p1;
        }
        {
            const unsigned int p4 = __shfl_xor(w[4], 32);
            const unsigned int p5 = __shfl_xor(w[5], 32);
            const unsigned int p6 = __shfl_xor(w[6], 32);
            const unsigned int p7 = __shfl_xor(w[7], 32);
            pb1.u[0] = l5 ? p6 : w[4];
            pb1.u[1] = l5 ? p7 : w[5];
            pb1.u[2] = l5 ? w[6] : p4;
            pb1.u[3] = l5 ? w[7] : p5;
        }

        // ---- O^T += V^T·P^T: 2 d-blocks x 2 key-chunks (keys wk*32+kc*16+..) ----
#pragma unroll
        for (int dblk = 0; dblk < 2; ++dblk) {
            const short8 va0 = *(const short8*)(Vb + vOff[dblk * 2 + 0]);
            oT[dblk] = __builtin_amdgcn_mfma_f32_32x32x16_bf16(va0, pb0.s, oT[dblk], 0, 0, 0);
            const short8 va1 = *(const short8*)(Vb + vOff[dblk * 2 + 1]);
            oT[dblk] = __builtin_amdgcn_mfma_f32_32x32x16_bf16(va1, pb1.s, oT[dblk], 0, 0, 0);
        }
    }

    // ---- combine lane halves: full 32-key sum for this wave's key-half ----
    lsum += __shfl_xor(lsum, 32);

    __syncthreads();                       // all waves done with K/V buffers

    // ---- cross-wave (key-half) reduction via LDS, then write out ----
    float* Ored = (float*)smem;            // [64 q][68 d] fp32 (17408 B)
    float* Lred = Ored + 64 * 68;          // [64]
    const int qrow = wq * 32 + q31;
    if (wk == 0) {
#pragma unroll
        for (int dblk = 0; dblk < 2; ++dblk)
#pragma unroll
            for (int j = 0; j < 4; ++j) {
                floatx4 v;
#pragma unroll
                for (int r = 0; r < 4; ++r) v[r] = oT[dblk][j * 4 + r];
                *(floatx4*)(Ored + (size_t)qrow * 68 + dblk * 32 + j * 8 + l5 * 4) = v;
            }
        if (lane < 32) Lred[qrow] = lsum;
    }
    __syncthreads();
    if (wk == 1) {
        const float linv = 1.0f / (lsum + Lred[qrow]);
#pragma unroll
        for (int dblk = 0; dblk < 2; ++dblk)
#pragma unroll
            for (int j = 0; j < 4; ++j) {
                const floatx4 o =
                    *(const floatx4*)(Ored + (size_t)qrow * 68 + dblk * 32 + j * 8 + l5 * 4);
                floatx4 r;
#pragma unroll
                for (int t = 0; t < 4; ++t)
                    r[t] = (o[t] + oT[dblk][j * 4 + t]) * linv;
                *(floatx4*)(out + (size_t)(b * Sdim + q0 + qrow) * Hdim
                            + h * HD + dblk * 32 + j * 8 + l5 * 4) = r;
            }
    }
}

extern "C" void kernel_launch(void* const* d_in, const int* in_sizes, int n_in,
                              void* d_out, int out_size, void* d_ws, size_t ws_size,
                              hipStream_t stream) {
    const float* X    = (const float*)d_in[0];
    const float* mask = (const float*)d_in[1];
    const float* Wq   = (const float*)d_in[2];
    const float* bq   = (const float*)d_in[3];
    const float* Wk   = (const float*)d_in[4];
    const float* Wv   = (const float*)d_in[5];
    const float* bv   = (const float*)d_in[6];
    float* out = (float*)d_out;

    // workspace: k [b,h,s,d] + v^T [b,h,d,s] bf16 -> 16 MiB total
    unsigned short* kws = (unsigned short*)d_ws;
    unsigned short* vws = kws + (size_t)4096 * 1024;

    qkv_proj_kernel<<<dim3(16, 64), 256, 0, stream>>>(
        Wq, Wk, Wv, bq, bv, X, (unsigned short*)d_out, kws, vws);
    attn_kernel<<<dim3(1024), 256, 0, stream>>>(
        kws, vws, mask, out);
}

// Round 8
// 191.651 us; speedup vs baseline: 1.1375x; 1.0701x over previous
//
#include <hip/hip_runtime.h>
#include <hip/hip_bf16.h>

typedef __attribute__((ext_vector_type(4))) short bfx4;
typedef __attribute__((ext_vector_type(8))) short short8;
typedef __attribute__((ext_vector_type(4))) float floatx4;
typedef __attribute__((ext_vector_type(16))) float f32x16;
typedef __attribute__((ext_vector_type(4))) unsigned int uintx4;

constexpr int Sdim = 2048;
constexpr int Hdim = 1024;
constexpr int NH   = 16;
constexpr int HD   = 64;

// fp32 -> bf16 round-half-up (1 add + shift)
__device__ __forceinline__ unsigned short f2bf(float f) {
    return (unsigned short)((__builtin_bit_cast(unsigned int, f) + 0x8000u) >> 16);
}

// 8 fp32 -> 8 bf16, round-half-up, packed with v_perm_b32
__device__ __forceinline__ short8 cvt8(const float* __restrict__ p) {
    uintx4 a = *(const uintx4*)p;
    uintx4 b = *(const uintx4*)(p + 4);
#pragma unroll
    for (int i = 0; i < 4; ++i) { a[i] += 0x8000u; b[i] += 0x8000u; }
    union { unsigned int u[4]; short8 s; } r;
    r.u[0] = __builtin_amdgcn_perm(a[1], a[0], 0x07060302u);
    r.u[1] = __builtin_amdgcn_perm(a[3], a[2], 0x07060302u);
    r.u[2] = __builtin_amdgcn_perm(b[1], b[0], 0x07060302u);
    r.u[3] = __builtin_amdgcn_perm(b[3], b[2], 0x07060302u);
    return r.s;
}

// async global->LDS, 16 B per lane; LDS dest = uniform base + lane*16
__device__ __forceinline__ void async16(const unsigned short* g, unsigned short* l) {
    __builtin_amdgcn_global_load_lds(
        (const __attribute__((address_space(1))) unsigned int*)g,
        (__attribute__((address_space(3))) unsigned int*)l,
        16, 0, 0);
}

// pack 2 f32 -> 2 bf16 (RNE) in one instruction
__device__ __forceinline__ unsigned int cvtpk(float lo, float hi) {
    unsigned int r;
    asm("v_cvt_pk_bf16_f32 %0, %1, %2" : "=v"(r) : "v"(lo), "v"(hi));
    return r;
}

// ---------------------------------------------------------------------------
// Kernel 0: cast X, Wq, Wk, Wv to bf16 in workspace (memory-bound, ~5 us).
// Same f2bf half-up rounding as the old in-loop cvt8 -> identical numerics.
// ---------------------------------------------------------------------------
__global__ __launch_bounds__(256) void cast_kernel(
    const float* __restrict__ X,
    const float* __restrict__ Wq,
    const float* __restrict__ Wk,
    const float* __restrict__ Wv,
    unsigned short* __restrict__ xb,
    unsigned short* __restrict__ wb)
{
    constexpr int XC = (2 * Sdim * Hdim) / 8;   // 524288 8-elem chunks
    constexpr int WC = (Hdim * Hdim) / 8;       // 131072 chunks per W
    const int stride = gridDim.x * blockDim.x;
    for (int c = blockIdx.x * blockDim.x + threadIdx.x; c < XC + 3 * WC; c += stride) {
        const float* src;
        unsigned short* dst;
        if (c < XC) {
            src = X + (size_t)c * 8;
            dst = xb + (size_t)c * 8;
        } else {
            const int wc = c - XC;
            const int w  = wc / WC;
            const int o  = wc - w * WC;
            src = (w == 0 ? Wq : (w == 1 ? Wk : Wv)) + (size_t)o * 8;
            dst = wb + (size_t)w * (Hdim * Hdim) + (size_t)o * 8;
        }
        *(short8*)dst = cvt8(src);
    }
}

// ---------------------------------------------------------------------------
// Kernel 1: merged Q/K/V projection. R7: staging now reads PRE-CAST bf16
// from workspace (4 x 16B loads + 4 LDS stores per thread per step; the
// 4 x cvt8 (~48 VALU) and 8 x fp32 loads are gone from the hot loop).
// LDS layout, MFMA loop, epilogues unchanged. LDS 40960 B -> 4 blocks/CU.
// grid = (16 heads, 64 m-tiles); block = 256.
// ---------------------------------------------------------------------------
__global__ __launch_bounds__(256, 4) void qkv_proj_kernel(
    const unsigned short* __restrict__ wbf,   // [3][1024][1024] bf16
    const float* __restrict__ bq,
    const float* __restrict__ bv,
    const unsigned short* __restrict__ xbf,   // [4096][1024] bf16
    unsigned short* __restrict__ qo,          // = d_out viewed as ushort
    unsigned short* __restrict__ ko,
    unsigned short* __restrict__ vo)
{
    __shared__ __align__(16) unsigned short smem[2 * 10240];  // 40960 B

    const int tid  = threadIdx.x;
    const int wave = tid >> 6;
    const int lane = tid & 63;
    const int quad = lane >> 4;
    const int l16  = lane & 15;

    const int h  = blockIdx.x;
    const int n0 = h * 64;
    const int m0 = blockIdx.y * 64;

    floatx4 acc[3][4];                   // [matrix][m-tile]
#pragma unroll
    for (int g = 0; g < 3; ++g)
#pragma unroll
        for (int mt = 0; mt < 4; ++mt) acc[g][mt] = (floatx4){0.f, 0.f, 0.f, 0.f};

    const int srow = tid >> 2;        // 0..63
    const int scol = (tid & 3) * 8;   // 0..24

    const unsigned short* Xr  = xbf + (size_t)(m0 + srow) * Hdim + scol;
    const unsigned short* Wr0 = wbf + (size_t)(n0 + srow) * Hdim + scol;
    const unsigned short* Wr1 = wbf + (size_t)(Hdim * Hdim)     + (size_t)(n0 + srow) * Hdim + scol;
    const unsigned short* Wr2 = wbf + (size_t)(2 * Hdim * Hdim) + (size_t)(n0 + srow) * Hdim + scol;

    {
        unsigned short* B0 = smem;
        *(short8*)(B0 +        srow * 40 + scol) = *(const short8*)Xr;
        *(short8*)(B0 + 2560 + srow * 40 + scol) = *(const short8*)Wr0;
        *(short8*)(B0 + 5120 + srow * 40 + scol) = *(const short8*)Wr1;
        *(short8*)(B0 + 7680 + srow * 40 + scol) = *(const short8*)Wr2;
    }

    for (int s = 0; s < 32; ++s) {
        __syncthreads();
        const unsigned short* buf = smem + (s & 1) * 10240;

        short8 px, p0, p1, p2;
        if (s < 31) {
            const int kn = (s + 1) * 32;
            px = *(const short8*)(Xr  + kn);
            p0 = *(const short8*)(Wr0 + kn);
            p1 = *(const short8*)(Wr1 + kn);
            p2 = *(const short8*)(Wr2 + kn);
        }

        const int boff = (wave * 16 + l16) * 40 + quad * 8;
        const short8 b0 = *(const short8*)(buf + 2560 + boff);
        const short8 b1 = *(const short8*)(buf + 5120 + boff);
        const short8 b2 = *(const short8*)(buf + 7680 + boff);
#pragma unroll
        for (int mt = 0; mt < 4; ++mt) {
            const short8 af = *(const short8*)(buf + (mt * 16 + l16) * 40 + quad * 8);
            acc[0][mt] = __builtin_amdgcn_mfma_f32_16x16x32_bf16(af, b0, acc[0][mt], 0, 0, 0);
            acc[1][mt] = __builtin_amdgcn_mfma_f32_16x16x32_bf16(af, b1, acc[1][mt], 0, 0, 0);
            acc[2][mt] = __builtin_amdgcn_mfma_f32_16x16x32_bf16(af, b2, acc[2][mt], 0, 0, 0);
        }

        if (s < 31) {
            unsigned short* nb = smem + ((s & 1) ^ 1) * 10240;
            *(short8*)(nb +        srow * 40 + scol) = px;
            *(short8*)(nb + 2560 + srow * 40 + scol) = p0;
            *(short8*)(nb + 5120 + srow * 40 + scol) = p1;
            *(short8*)(nb + 7680 + srow * 40 + scol) = p2;
        }
    }

    const int b  = m0 >> 11;
    const int s0 = m0 & 2047;
    const int dd = wave * 16 + l16;

    {
        const float bqv = bq[n0 + dd];
#pragma unroll
        for (int mt = 0; mt < 4; ++mt)
#pragma unroll
            for (int reg = 0; reg < 4; ++reg) {
                const int srw = s0 + mt * 16 + quad * 4 + reg;
                qo[((size_t)(b * Sdim + srw) * Hdim + n0) * 2 + dd] =
                    f2bf((acc[0][mt][reg] + bqv) * 0.125f);
            }
    }
#pragma unroll
    for (int mt = 0; mt < 4; ++mt)
#pragma unroll
        for (int reg = 0; reg < 4; ++reg) {
            const int srw = s0 + mt * 16 + quad * 4 + reg;
            ko[((size_t)(b * NH + h) * Sdim + srw) * HD + dd] = f2bf(acc[1][mt][reg]);
        }
    unsigned short* Vl = smem;   // 64*74 shorts
    {
        const float bvv = bv[n0 + dd];
#pragma unroll
        for (int mt = 0; mt < 4; ++mt) {
            bfx4 p;
#pragma unroll
            for (int reg = 0; reg < 4; ++reg) p[reg] = (short)f2bf(acc[2][mt][reg] + bvv);
            *(bfx4*)(Vl + dd * 74 + mt * 16 + quad * 4) = p;
        }
    }
    __syncthreads();
#pragma unroll
    for (int i = 0; i < 2; ++i) {
        const int t   = tid + 256 * i;
        const int d2  = t >> 3;
        const int off = (t & 7) * 8;
        *(short8*)(vo + ((size_t)(b * NH + h) * HD + d2) * Sdim + s0 + off) =
            *(const short8*)(Vl + d2 * 74 + off);
    }
}

// ---------------------------------------------------------------------------
// Kernel 2: flash attention on 32x32x16 MFMA (UNCHANGED from R6 — control).
// ---------------------------------------------------------------------------
__global__ __launch_bounds__(256) void attn_kernel(
    const unsigned short* __restrict__ kw,
    const unsigned short* __restrict__ vw,
    const float* __restrict__ mask,
    float* __restrict__ out)
{
    __shared__ __align__(16) unsigned short smem[16384];   // 32768 B
    unsigned short* KtA = smem;            // 2 x 4096 shorts (64 keys x 64 d, swizzled)
    unsigned short* VtA = smem + 8192;     // 2 x 4096 shorts (64 d x 64 keys, swizzled)

    const int tid  = threadIdx.x;
    const int wave = tid >> 6;
    const int wq   = wave >> 1;            // q-half 0/1
    const int wk   = wave & 1;             // key-half 0/1
    const int lane = tid & 63;
    const int l5   = lane >> 5;            // lane-half
    const int q31  = lane & 31;            // this lane's q column (C layout)
    const int m7l  = lane & 7;

    const int flat = blockIdx.x;
    const int bh   = flat & 31;
    const int b    = bh >> 4;
    const int h    = bh & 15;
    const int q0   = (flat >> 5) * 64;

    const unsigned short* K  = kw + (size_t)bh * Sdim * HD;   // [key][d]
    const unsigned short* Vg = vw + (size_t)bh * HD * Sdim;   // [d][key]
    const float* mg = mask + (size_t)b * Sdim;

    constexpr float SHIFT = 12.0f;

    // ---- Q fragments (B-operand, 32x32x16): lane holds col q31, k = i*16+l5*8 ----
    short8 qf[4];
    {
        const unsigned short* qsrc = (const unsigned short*)out;
        const size_t qbase =
            ((size_t)(b * Sdim + q0 + wq * 32 + q31) * Hdim + h * HD) * 2;
#pragma unroll
        for (int i = 0; i < 4; ++i)
            qf[i] = *(const short8*)(qsrc + qbase + i * 16 + l5 * 8);
    }

    // ---- DMA lane mapping: lane covers row rk, global chunk XOR-swizzled ----
    const int rk = wave * 16 + (lane >> 3);
    const int sw = ((lane & 7) ^ (rk & 7)) * 8;
    const unsigned short* kgp = K  + (size_t)rk * HD   + sw;
    const unsigned short* vgp = Vg + (size_t)rk * Sdim + sw;

    // stage tile 0 -> buffer 0
    {
        unsigned short* Kb = KtA + wave * 1024;
        unsigned short* Vb = VtA + wave * 1024;
        async16(kgp,            Kb);
        async16(kgp + 8 * HD,   Kb + 512);
        async16(vgp,            Vb);
        async16(vgp + 8 * Sdim, Vb + 512);
        kgp += (size_t)64 * HD;
        vgp += 64;
    }

    // tile-invariant LDS read offsets (shorts); row&7 == lane&7 for both
    int kOff[4], vOff[4];
#pragma unroll
    for (int i = 0; i < 4; ++i)
        kOff[i] = (wk * 32 + q31) * 64 + (((2 * i + l5) ^ m7l) * 8);
#pragma unroll
    for (int dblk = 0; dblk < 2; ++dblk)
#pragma unroll
        for (int kc = 0; kc < 2; ++kc)
            vOff[dblk * 2 + kc] =
                (dblk * 32 + q31) * 64 + (((wk * 4 + 2 * kc + l5) ^ m7l) * 8);

    const float* mgp = mg + wk * 32 + l5 * 4;

    float lsum = 0.f;
    f32x16 oT[2];                          // O^T per 32-d block; col=q31
#pragma unroll
    for (int dblk = 0; dblk < 2; ++dblk)
#pragma unroll
        for (int r = 0; r < 16; ++r) oT[dblk][r] = 0.f;

    for (int it = 0; it < 32; ++it) {
        __syncthreads();                   // vmcnt drain + barrier: tile ready
        const int kt = it * 64;
        const unsigned short* Kb = KtA + (it & 1) * 4096;
        const unsigned short* Vb = VtA + (it & 1) * 4096;

        if (it < 31) {                     // DMA next tile into other buffer
            unsigned short* Kn = KtA + ((it & 1) ^ 1) * 4096 + wave * 1024;
            unsigned short* Vn = VtA + ((it & 1) ^ 1) * 4096 + wave * 1024;
            async16(kgp,            Kn);
            async16(kgp + 8 * HD,   Kn + 512);
            async16(vgp,            Vn);
            async16(vgp + 8 * Sdim, Vn + 512);
            kgp += (size_t)64 * HD;
            vgp += 64;
        }

        // ---- S^T = K·Q^T: 4 chained 32x32x16 over d ----
        f32x16 st;
#pragma unroll
        for (int r = 0; r < 16; ++r) st[r] = 0.f;
#pragma unroll
        for (int i = 0; i < 4; ++i) {
            const short8 ka = *(const short8*)(Kb + kOff[i]);
            st = __builtin_amdgcn_mfma_f32_32x32x16_bf16(ka, qf[i], st, 0, 0, 0);
        }

        // ---- exp + in-register bf16 pack; st reg r -> key row (r&3)+8*(r>>2)+4*l5
        unsigned int w[8];
#pragma unroll
        for (int j = 0; j < 4; ++j) {
            const floatx4 mv = *(const floatx4*)(mgp + kt + j * 8);
            float e[4];
#pragma unroll
            for (int r = 0; r < 4; ++r) {
                e[r] = __expf(st[j * 4 + r] + (mv[r] - SHIFT));
                lsum += e[r];
            }
            w[2 * j]     = cvtpk(e[0], e[1]);
            w[2 * j + 1] = cvtpk(e[2], e[3]);
        }

        // ---- cross-half exchange: shfl_xor(32) + select ----
        // lane owns keys kc*16 + {4*l5+0..3, 8+4*l5+0..3}; B-frag needs l5*8+0..7
        union { unsigned int u[4]; short8 s; } pb0, pb1;
        {
            const unsigned int p0 = __shfl_xor(w[0], 32);
            const unsigned int p1 = __shfl_xor(w[1], 32);
            const unsigned int p2 = __shfl_xor(w[2], 32);
            const unsigned int p3 = __shfl_xor(w[3], 32);
            pb0.u[0] = l5 ? p2 : w[0];
            pb0.u[1] = l5 ? p3 : w[1];
            pb0.u[2] = l5 ? w[2] : p0;
            pb0.u[3] = l5 ? w[3] : p1;
        }
        {
            const unsigned int p4 = __shfl_xor(w[4], 32);
            const unsigned int p5 = __shfl_xor(w[5], 32);
            const unsigned int p6 = __shfl_xor(w[6], 32);
            const unsigned int p7 = __shfl_xor(w[7], 32);
            pb1.u[0] = l5 ? p6 : w[4];
            pb1.u[1] = l5 ? p7 : w[5];
            pb1.u[2] = l5 ? w[6] : p4;
            pb1.u[3] = l5 ? w[7] : p5;
        }

        // ---- O^T += V^T·P^T: 2 d-blocks x 2 key-chunks (keys wk*32+kc*16+..) ----
#pragma unroll
        for (int dblk = 0; dblk < 2; ++dblk) {
            const short8 va0 = *(const short8*)(Vb + vOff[dblk * 2 + 0]);
            oT[dblk] = __builtin_amdgcn_mfma_f32_32x32x16_bf16(va0, pb0.s, oT[dblk], 0, 0, 0);
            const short8 va1 = *(const short8*)(Vb + vOff[dblk * 2 + 1]);
            oT[dblk] = __builtin_amdgcn_mfma_f32_32x32x16_bf16(va1, pb1.s, oT[dblk], 0, 0, 0);
        }
    }

    // ---- combine lane halves: full 32-key sum for this wave's key-half ----
    lsum += __shfl_xor(lsum, 32);

    __syncthreads();                       // all waves done with K/V buffers

    // ---- cross-wave (key-half) reduction via LDS, then write out ----
    float* Ored = (float*)smem;            // [64 q][68 d] fp32 (17408 B)
    float* Lred = Ored + 64 * 68;          // [64]
    const int qrow = wq * 32 + q31;
    if (wk == 0) {
#pragma unroll
        for (int dblk = 0; dblk < 2; ++dblk)
#pragma unroll
            for (int j = 0; j < 4; ++j) {
                floatx4 v;
#pragma unroll
                for (int r = 0; r < 4; ++r) v[r] = oT[dblk][j * 4 + r];
                *(floatx4*)(Ored + (size_t)qrow * 68 + dblk * 32 + j * 8 + l5 * 4) = v;
            }
        if (lane < 32) Lred[qrow] = lsum;
    }
    __syncthreads();
    if (wk == 1) {
        const float linv = 1.0f / (lsum + Lred[qrow]);
#pragma unroll
        for (int dblk = 0; dblk < 2; ++dblk)
#pragma unroll
            for (int j = 0; j < 4; ++j) {
                const floatx4 o =
                    *(const floatx4*)(Ored + (size_t)qrow * 68 + dblk * 32 + j * 8 + l5 * 4);
                floatx4 r;
#pragma unroll
                for (int t = 0; t < 4; ++t)
                    r[t] = (o[t] + oT[dblk][j * 4 + t]) * linv;
                *(floatx4*)(out + (size_t)(b * Sdim + q0 + qrow) * Hdim
                            + h * HD + dblk * 32 + j * 8 + l5 * 4) = r;
            }
    }
}

extern "C" void kernel_launch(void* const* d_in, const int* in_sizes, int n_in,
                              void* d_out, int out_size, void* d_ws, size_t ws_size,
                              hipStream_t stream) {
    const float* X    = (const float*)d_in[0];
    const float* mask = (const float*)d_in[1];
    const float* Wq   = (const float*)d_in[2];
    const float* bq   = (const float*)d_in[3];
    const float* Wk   = (const float*)d_in[4];
    const float* Wv   = (const float*)d_in[5];
    const float* bv   = (const float*)d_in[6];
    float* out = (float*)d_out;

    // workspace (30 MiB): k 8 + v^T 8 + X_bf16 8 + W_bf16 6
    unsigned short* kws = (unsigned short*)d_ws;
    unsigned short* vws = kws + (size_t)4096 * 1024;
    unsigned short* xb  = vws + (size_t)4096 * 1024;
    unsigned short* wb  = xb  + (size_t)2 * Sdim * Hdim;

    cast_kernel<<<dim3(2048), 256, 0, stream>>>(X, Wq, Wk, Wv, xb, wb);
    qkv_proj_kernel<<<dim3(16, 64), 256, 0, stream>>>(
        wb, bq, bv, xb, (unsigned short*)d_out, kws, vws);
    attn_kernel<<<dim3(1024), 256, 0, stream>>>(
        kws, vws, mask, out);
}

// Round 12
// 189.464 us; speedup vs baseline: 1.1506x; 1.0115x over previous
//
#include <hip/hip_runtime.h>
#include <hip/hip_bf16.h>

typedef __attribute__((ext_vector_type(4))) short bfx4;
typedef __attribute__((ext_vector_type(8))) short short8;
typedef __attribute__((ext_vector_type(4))) float floatx4;
typedef __attribute__((ext_vector_type(16))) float f32x16;
typedef __attribute__((ext_vector_type(4))) unsigned int uintx4;

constexpr int Sdim = 2048;
constexpr int Hdim = 1024;
constexpr int NH   = 16;
constexpr int HD   = 64;

// fp32 -> bf16 round-half-up (1 add + shift)
__device__ __forceinline__ unsigned short f2bf(float f) {
    return (unsigned short)((__builtin_bit_cast(unsigned int, f) + 0x8000u) >> 16);
}

// 8 fp32 -> 8 bf16, round-half-up, packed with v_perm_b32
__device__ __forceinline__ short8 cvt8(const float* __restrict__ p) {
    uintx4 a = *(const uintx4*)p;
    uintx4 b = *(const uintx4*)(p + 4);
#pragma unroll
    for (int i = 0; i < 4; ++i) { a[i] += 0x8000u; b[i] += 0x8000u; }
    union { unsigned int u[4]; short8 s; } r;
    r.u[0] = __builtin_amdgcn_perm(a[1], a[0], 0x07060302u);
    r.u[1] = __builtin_amdgcn_perm(a[3], a[2], 0x07060302u);
    r.u[2] = __builtin_amdgcn_perm(b[1], b[0], 0x07060302u);
    r.u[3] = __builtin_amdgcn_perm(b[3], b[2], 0x07060302u);
    return r.s;
}

// async global->LDS, 16 B per lane; LDS dest = uniform base + lane*16
__device__ __forceinline__ void async16(const unsigned short* g, unsigned short* l) {
    __builtin_amdgcn_global_load_lds(
        (const __attribute__((address_space(1))) unsigned int*)g,
        (__attribute__((address_space(3))) unsigned int*)l,
        16, 0, 0);
}

// pack 2 f32 -> 2 bf16 (RNE) in one instruction
__device__ __forceinline__ unsigned int cvtpk(float lo, float hi) {
    unsigned int r;
    asm("v_cvt_pk_bf16_f32 %0, %1, %2" : "=v"(r) : "v"(lo), "v"(hi));
    return r;
}

// ---------------------------------------------------------------------------
// Kernel 0: cast X, Wq, Wk, Wv to bf16 in workspace (memory-bound, ~5 us).
// ---------------------------------------------------------------------------
__global__ __launch_bounds__(256) void cast_kernel(
    const float* __restrict__ X,
    const float* __restrict__ Wq,
    const float* __restrict__ Wk,
    const float* __restrict__ Wv,
    unsigned short* __restrict__ xb,
    unsigned short* __restrict__ wb)
{
    constexpr int XC = (2 * Sdim * Hdim) / 8;   // 524288 8-elem chunks
    constexpr int WC = (Hdim * Hdim) / 8;       // 131072 chunks per W
    const int stride = gridDim.x * blockDim.x;
    for (int c = blockIdx.x * blockDim.x + threadIdx.x; c < XC + 3 * WC; c += stride) {
        const float* src;
        unsigned short* dst;
        if (c < XC) {
            src = X + (size_t)c * 8;
            dst = xb + (size_t)c * 8;
        } else {
            const int wc = c - XC;
            const int w  = wc / WC;
            const int o  = wc - w * WC;
            src = (w == 0 ? Wq : (w == 1 ? Wk : Wv)) + (size_t)o * 8;
            dst = wb + (size_t)w * (Hdim * Hdim) + (size_t)o * 8;
        }
        *(short8*)dst = cvt8(src);
    }
}

// ---------------------------------------------------------------------------
// Kernel 1: merged Q/K/V projection. R9: staging via global_load_lds DMA.
// Each wave stages ONE matrix tile (w0=X, w1..3=W) per step: 4 async16 calls
// of 16 rows (64 B/row) each. LDS image is chunk-swizzled: stored(r,c) =
// orig(r, c ^ f(r)), f(r) = (r>>1)&3, realized by permuting the GLOBAL
// source chunk per lane (LDS dest stays linear). Fragment reads use the same
// XOR -> 8 distinct 16B bank-starts covering all 32 banks (conflict-free,
// same distribution as the old +40 padding). No reg round-trip, no
// ds_writes, -16 VGPR. LDS 2 x 16 KiB = 32 KiB.
// grid = (16 heads, 64 m-tiles); block = 256.
// ---------------------------------------------------------------------------
__global__ __launch_bounds__(256, 4) void qkv_proj_kernel(
    const unsigned short* __restrict__ wbf,   // [3][1024][1024] bf16
    const float* __restrict__ bq,
    const float* __restrict__ bv,
    const unsigned short* __restrict__ xbf,   // [4096][1024] bf16
    unsigned short* __restrict__ qo,          // = d_out viewed as ushort
    unsigned short* __restrict__ ko,
    unsigned short* __restrict__ vo)
{
    __shared__ __align__(16) unsigned short smem[2 * 8192];   // 32768 B
    // buffer p: +p*8192 shorts; tiles: X +0, W0 +2048, W1 +4096, W2 +6144

    const int tid  = threadIdx.x;
    const int wave = tid >> 6;
    const int lane = tid & 63;
    const int quad = lane >> 4;
    const int l16  = lane & 15;

    const int h  = blockIdx.x;
    const int n0 = h * 64;
    const int m0 = blockIdx.y * 64;

    floatx4 acc[3][4];                   // [matrix][m-tile]
#pragma unroll
    for (int g = 0; g < 3; ++g)
#pragma unroll
        for (int mt = 0; mt < 4; ++mt) acc[g][mt] = (floatx4){0.f, 0.f, 0.f, 0.f};

    // ---- DMA source mapping: lane -> row j*16 + (lane>>2), chunk lane&3 ----
    const int drow   = lane >> 2;            // 0..15
    const int dchunk = lane & 3;
    const int fD     = (drow >> 1) & 3;      // (row>>1)&3; j*16 doesn't affect it
    const unsigned short* gbase = (wave == 0)
        ? xbf + (size_t)m0 * Hdim
        : wbf + (size_t)(wave - 1) * (Hdim * Hdim) + (size_t)n0 * Hdim;
    const unsigned short* gp =
        gbase + (size_t)drow * Hdim + ((dchunk ^ fD) * 8);

    // stage step 0 -> buffer 0 (wave stages its own 4 KiB tile)
    {
        unsigned short* db = smem + wave * 2048;
#pragma unroll
        for (int j = 0; j < 4; ++j)
            async16(gp + (size_t)(j * 16) * Hdim, db + j * 512);
    }

    // fragment read offset (shorts), step-invariant; f = (l16>>1)&3 since
    // mt*16 / wave*16 don't touch bits 1..2 of the row
    const int fR   = (l16 >> 1) & 3;
    const int cswz = (quad ^ fR) * 8;
    const int boff = (wave * 16 + l16) * 32 + cswz;

    for (int s = 0; s < 32; ++s) {
        __syncthreads();                              // drain DMA: tile s ready
        const unsigned short* buf = smem + (s & 1) * 8192;

        if (s < 31) {                                 // DMA next step -> other buffer
            unsigned short* nb = smem + ((s & 1) ^ 1) * 8192 + wave * 2048;
            const unsigned short* g = gp + (s + 1) * 32;
#pragma unroll
            for (int j = 0; j < 4; ++j)
                async16(g + (size_t)(j * 16) * Hdim, nb + j * 512);
        }

        const short8 b0 = *(const short8*)(buf + 2048 + boff);
        const short8 b1 = *(const short8*)(buf + 4096 + boff);
        const short8 b2 = *(const short8*)(buf + 6144 + boff);
#pragma unroll
        for (int mt = 0; mt < 4; ++mt) {
            const short8 af = *(const short8*)(buf + (mt * 16 + l16) * 32 + cswz);
            acc[0][mt] = __builtin_amdgcn_mfma_f32_16x16x32_bf16(af, b0, acc[0][mt], 0, 0, 0);
            acc[1][mt] = __builtin_amdgcn_mfma_f32_16x16x32_bf16(af, b1, acc[1][mt], 0, 0, 0);
            acc[2][mt] = __builtin_amdgcn_mfma_f32_16x16x32_bf16(af, b2, acc[2][mt], 0, 0, 0);
        }
    }

    const int b  = m0 >> 11;
    const int s0 = m0 & 2047;
    const int dd = wave * 16 + l16;

    // ---- Q epilogue: bf16 packed into the block's own d_out region ----
    {
        const float bqv = bq[n0 + dd];
#pragma unroll
        for (int mt = 0; mt < 4; ++mt)
#pragma unroll
            for (int reg = 0; reg < 4; ++reg) {
                const int srw = s0 + mt * 16 + quad * 4 + reg;
                qo[((size_t)(b * Sdim + srw) * Hdim + n0) * 2 + dd] =
                    f2bf((acc[0][mt][reg] + bqv) * 0.125f);
            }
    }
    // ---- K epilogue: bf16 [b,h,s,d] ----
#pragma unroll
    for (int mt = 0; mt < 4; ++mt)
#pragma unroll
        for (int reg = 0; reg < 4; ++reg) {
            const int srw = s0 + mt * 16 + quad * 4 + reg;
            ko[((size_t)(b * NH + h) * Sdim + srw) * HD + dd] = f2bf(acc[1][mt][reg]);
        }
    // ---- V epilogue: transpose via LDS buf0 (last step read buf1: disjoint) ----
    unsigned short* Vl = smem;   // 64*74 shorts = 4736 <= 8192
    {
        const float bvv = bv[n0 + dd];
#pragma unroll
        for (int mt = 0; mt < 4; ++mt) {
            bfx4 p;
#pragma unroll
            for (int reg = 0; reg < 4; ++reg) p[reg] = (short)f2bf(acc[2][mt][reg] + bvv);
            *(bfx4*)(Vl + dd * 74 + mt * 16 + quad * 4) = p;
        }
    }
    __syncthreads();
#pragma unroll
    for (int i = 0; i < 2; ++i) {
        const int t   = tid + 256 * i;
        const int d2  = t >> 3;
        const int off = (t & 7) * 8;
        *(short8*)(vo + ((size_t)(b * NH + h) * HD + d2) * Sdim + s0 + off) =
            *(const short8*)(Vl + d2 * 74 + off);
    }
}

// ---------------------------------------------------------------------------
// Kernel 2: flash attention on 32x32x16 MFMA. R9: cross-half exchange via
// v_permlane32_swap (4 instrs), replacing 8 shfl_xor (ds_bpermute) + 8
// cndmask. PROVEN equivalent: R3 (permlane) and R4 (shfl+select) produced
// bit-identical outputs; R4's exchange passed in R6 once vOff was fixed.
// ---------------------------------------------------------------------------
__global__ __launch_bounds__(256) void attn_kernel(
    const unsigned short* __restrict__ kw,
    const unsigned short* __restrict__ vw,
    const float* __restrict__ mask,
    float* __restrict__ out)
{
    __shared__ __align__(16) unsigned short smem[16384];   // 32768 B
    unsigned short* KtA = smem;            // 2 x 4096 shorts (64 keys x 64 d, swizzled)
    unsigned short* VtA = smem + 8192;     // 2 x 4096 shorts (64 d x 64 keys, swizzled)

    const int tid  = threadIdx.x;
    const int wave = tid >> 6;
    const int wq   = wave >> 1;            // q-half 0/1
    const int wk   = wave & 1;             // key-half 0/1
    const int lane = tid & 63;
    const int l5   = lane >> 5;            // lane-half
    const int q31  = lane & 31;            // this lane's q column (C layout)
    const int m7l  = lane & 7;

    const int flat = blockIdx.x;
    const int bh   = flat & 31;
    const int b    = bh >> 4;
    const int h    = bh & 15;
    const int q0   = (flat >> 5) * 64;

    const unsigned short* K  = kw + (size_t)bh * Sdim * HD;   // [key][d]
    const unsigned short* Vg = vw + (size_t)bh * HD * Sdim;   // [d][key]
    const float* mg = mask + (size_t)b * Sdim;

    constexpr float SHIFT = 12.0f;

    // ---- Q fragments (B-operand, 32x32x16): lane holds col q31, k = i*16+l5*8 ----
    short8 qf[4];
    {
        const unsigned short* qsrc = (const unsigned short*)out;
        const size_t qbase =
            ((size_t)(b * Sdim + q0 + wq * 32 + q31) * Hdim + h * HD) * 2;
#pragma unroll
        for (int i = 0; i < 4; ++i)
            qf[i] = *(const short8*)(qsrc + qbase + i * 16 + l5 * 8);
    }

    // ---- DMA lane mapping: lane covers row rk, global chunk XOR-swizzled ----
    const int rk = wave * 16 + (lane >> 3);
    const int sw = ((lane & 7) ^ (rk & 7)) * 8;
    const unsigned short* kgp = K  + (size_t)rk * HD   + sw;
    const unsigned short* vgp = Vg + (size_t)rk * Sdim + sw;

    // stage tile 0 -> buffer 0
    {
        unsigned short* Kb = KtA + wave * 1024;
        unsigned short* Vb = VtA + wave * 1024;
        async16(kgp,            Kb);
        async16(kgp + 8 * HD,   Kb + 512);
        async16(vgp,            Vb);
        async16(vgp + 8 * Sdim, Vb + 512);
        kgp += (size_t)64 * HD;
        vgp += 64;
    }

    // tile-invariant LDS read offsets (shorts); row&7 == lane&7 for both
    int kOff[4], vOff[4];
#pragma unroll
    for (int i = 0; i < 4; ++i)
        kOff[i] = (wk * 32 + q31) * 64 + (((2 * i + l5) ^ m7l) * 8);
#pragma unroll
    for (int dblk = 0; dblk < 2; ++dblk)
#pragma unroll
        for (int kc = 0; kc < 2; ++kc)
            vOff[dblk * 2 + kc] =
                (dblk * 32 + q31) * 64 + (((wk * 4 + 2 * kc + l5) ^ m7l) * 8);

    const float* mgp = mg + wk * 32 + l5 * 4;

    float lsum = 0.f;
    f32x16 oT[2];                          // O^T per 32-d block; col=q31
#pragma unroll
    for (int dblk = 0; dblk < 2; ++dblk)
#pragma unroll
        for (int r = 0; r < 16; ++r) oT[dblk][r] = 0.f;

    for (int it = 0; it < 32; ++it) {
        __syncthreads();                   // vmcnt drain + barrier: tile ready
        const int kt = it * 64;
        const unsigned short* Kb = KtA + (it & 1) * 4096;
        const unsigned short* Vb = VtA + (it & 1) * 4096;

        if (it < 31) {                     // DMA next tile into other buffer
            unsigned short* Kn = KtA + ((it & 1) ^ 1) * 4096 + wave * 1024;
            unsigned short* Vn = VtA + ((it & 1) ^ 1) * 4096 + wave * 1024;
            async16(kgp,            Kn);
            async16(kgp + 8 * HD,   Kn + 512);
            async16(vgp,            Vn);
            async16(vgp + 8 * Sdim, Vn + 512);
            kgp += (size_t)64 * HD;
            vgp += 64;
        }

        // ---- S^T = K·Q^T: 4 chained 32x32x16 over d ----
        f32x16 st;
#pragma unroll
        for (int r = 0; r < 16; ++r) st[r] = 0.f;
#pragma unroll
        for (int i = 0; i < 4; ++i) {
            const short8 ka = *(const short8*)(Kb + kOff[i]);
            st = __builtin_amdgcn_mfma_f32_32x32x16_bf16(ka, qf[i], st, 0, 0, 0);
        }

        // ---- exp + in-register bf16 pack; st reg r -> key row (r&3)+8*(r>>2)+4*l5
        unsigned int w[8];
#pragma unroll
        for (int j = 0; j < 4; ++j) {
            const floatx4 mv = *(const floatx4*)(mgp + kt + j * 8);
            float e[4];
#pragma unroll
            for (int r = 0; r < 4; ++r) {
                e[r] = __expf(st[j * 4 + r] + (mv[r] - SHIFT));
                lsum += e[r];
            }
            w[2 * j]     = cvtpk(e[0], e[1]);
            w[2 * j + 1] = cvtpk(e[2], e[3]);
        }

        // ---- cross-half exchange: 4 x v_permlane32_swap (proven = R6 select) ----
        asm("v_permlane32_swap_b32 %0, %1" : "+v"(w[0]), "+v"(w[2]));
        asm("v_permlane32_swap_b32 %0, %1" : "+v"(w[1]), "+v"(w[3]));
        asm("v_permlane32_swap_b32 %0, %1" : "+v"(w[4]), "+v"(w[6]));
        asm("v_permlane32_swap_b32 %0, %1" : "+v"(w[5]), "+v"(w[7]));
        union { unsigned int u[4]; short8 s; } pb0, pb1;
#pragma unroll
        for (int r = 0; r < 4; ++r) { pb0.u[r] = w[r]; pb1.u[r] = w[4 + r]; }

        // ---- O^T += V^T·P^T: 2 d-blocks x 2 key-chunks (keys wk*32+kc*16+..) ----
#pragma unroll
        for (int dblk = 0; dblk < 2; ++dblk) {
            const short8 va0 = *(const short8*)(Vb + vOff[dblk * 2 + 0]);
            oT[dblk] = __builtin_amdgcn_mfma_f32_32x32x16_bf16(va0, pb0.s, oT[dblk], 0, 0, 0);
            const short8 va1 = *(const short8*)(Vb + vOff[dblk * 2 + 1]);
            oT[dblk] = __builtin_amdgcn_mfma_f32_32x32x16_bf16(va1, pb1.s, oT[dblk], 0, 0, 0);
        }
    }

    // ---- combine lane halves: full 32-key sum for this wave's key-half ----
    lsum += __shfl_xor(lsum, 32);

    __syncthreads();                       // all waves done with K/V buffers

    // ---- cross-wave (key-half) reduction via LDS, then write out ----
    float* Ored = (float*)smem;            // [64 q][68 d] fp32 (17408 B)
    float* Lred = Ored + 64 * 68;          // [64]
    const int qrow = wq * 32 + q31;
    if (wk == 0) {
#pragma unroll
        for (int dblk = 0; dblk < 2; ++dblk)
#pragma unroll
            for (int j = 0; j < 4; ++j) {
                floatx4 v;
#pragma unroll
                for (int r = 0; r < 4; ++r) v[r] = oT[dblk][j * 4 + r];
                *(floatx4*)(Ored + (size_t)qrow * 68 + dblk * 32 + j * 8 + l5 * 4) = v;
            }
        if (lane < 32) Lred[qrow] = lsum;
    }
    __syncthreads();
    if (wk == 1) {
        const float linv = 1.0f / (lsum + Lred[qrow]);
#pragma unroll
        for (int dblk = 0; dblk < 2; ++dblk)
#pragma unroll
            for (int j = 0; j < 4; ++j) {
                const floatx4 o =
                    *(const floatx4*)(Ored + (size_t)qrow * 68 + dblk * 32 + j * 8 + l5 * 4);
                floatx4 r;
#pragma unroll
                for (int t = 0; t < 4; ++t)
                    r[t] = (o[t] + oT[dblk][j * 4 + t]) * linv;
                *(floatx4*)(out + (size_t)(b * Sdim + q0 + qrow) * Hdim
                            + h * HD + dblk * 32 + j * 8 + l5 * 4) = r;
            }
    }
}

extern "C" void kernel_launch(void* const* d_in, const int* in_sizes, int n_in,
                              void* d_out, int out_size, void* d_ws, size_t ws_size,
                              hipStream_t stream) {
    const float* X    = (const float*)d_in[0];
    const float* mask = (const float*)d_in[1];
    const float* Wq   = (const float*)d_in[2];
    const float* bq   = (const float*)d_in[3];
    const float* Wk   = (const float*)d_in[4];
    const float* Wv   = (const float*)d_in[5];
    const float* bv   = (const float*)d_in[6];
    float* out = (float*)d_out;

    // workspace (30 MiB): k 8 + v^T 8 + X_bf16 8 + W_bf16 6
    unsigned short* kws = (unsigned short*)d_ws;
    unsigned short* vws = kws + (size_t)4096 * 1024;
    unsigned short* xb  = vws + (size_t)4096 * 1024;
    unsigned short* wb  = xb  + (size_t)2 * Sdim * Hdim;

    cast_kernel<<<dim3(2048), 256, 0, stream>>>(X, Wq, Wk, Wv, xb, wb);
    qkv_proj_kernel<<<dim3(16, 64), 256, 0, stream>>>(
        wb, bq, bv, xb, (unsigned short*)d_out, kws, vws);
    attn_kernel<<<dim3(1024), 256, 0, stream>>>(
        kws, vws, mask, out);
}